// Round 4
// baseline (3752.092 us; speedup 1.0000x reference)
//
#include <hip/hip_runtime.h>
#include <hip/hip_bf16.h>

// GRU (TF GRUCell), B=2048, T=12, D=512, H=1024, fp32 in/out.
// R4: recurrence fused into ONE persistent kernel (512 blocks, hand-rolled
// device-scope grid barrier) -> no per-step launch ramp/cold-cache/drain.
// Px precompute kernel unchanged from R3. XOR-swizzled A-LDS (conflict-free).

#define T_SEQ 12
#define BATCH 2048
#define IND 512
#define HID 1024
#define NGATE (2 * HID)  // 2048
#define NPRE (NGATE + HID)
#define NBLK 512

typedef __bf16 bf16x8 __attribute__((ext_vector_type(8)));
typedef __bf16 bf16x4 __attribute__((ext_vector_type(4)));
typedef float floatx4 __attribute__((ext_vector_type(4)));

__device__ __forceinline__ float fast_sigmoid(float v) {
  v = fminf(30.f, fmaxf(-30.f, v));
  return 1.f / (1.f + __expf(-v));
}
__device__ __forceinline__ float fast_tanh(float v) {
  v = fminf(15.f, fmaxf(-15.f, v));
  float e = __expf(2.f * v);
  return (e - 1.f) / (e + 1.f);
}

// ---------------- setup kernels (unchanged from R3) ----------------
__global__ void pack_w(const float* __restrict__ W, int ld, int row0, int ksteps,
                       __bf16* __restrict__ out) {
  int gid = blockIdx.x * blockDim.x + threadIdx.x;
  int wid = gid >> 6;
  int lane = gid & 63;
  int n16 = wid / ksteps;
  int ktile = wid - n16 * ksteps;
  int col = n16 * 16 + (lane & 15);
  int k0 = row0 + ktile * 32 + (lane >> 4) * 8;
  bf16x8 v;
#pragma unroll
  for (int j = 0; j < 8; ++j) v[j] = (__bf16)W[(size_t)(k0 + j) * ld + col];
  *reinterpret_cast<bf16x8*>(out + (size_t)wid * 512 + lane * 8) = v;
}

__global__ void cvt_bf16(const float4* __restrict__ in, __bf16* __restrict__ out, int n4) {
  int i = blockIdx.x * blockDim.x + threadIdx.x;
  if (i >= n4) return;
  float4 v = in[i];
  bf16x4 o;
  o[0] = (__bf16)v.x; o[1] = (__bf16)v.y; o[2] = (__bf16)v.z; o[3] = (__bf16)v.w;
  *reinterpret_cast<bf16x4*>(out + (size_t)i * 4) = o;
}

__global__ void init_h(const float4* __restrict__ coded, float4* __restrict__ h32,
                       __bf16* __restrict__ hb, int n4) {
  int i = blockIdx.x * blockDim.x + threadIdx.x;
  if (i >= n4) return;
  float4 v = coded[i];
  h32[i] = v;
  bf16x4 o;
  o[0] = (__bf16)v.x; o[1] = (__bf16)v.y; o[2] = (__bf16)v.z; o[3] = (__bf16)v.w;
  *reinterpret_cast<bf16x4*>(hb + (size_t)i * 4) = o;
}

// ---------------- Px precompute (R3 gk MODE0, hardcoded) ----------------
// grid(24, 32, 12), 256 thr. Block tile 64x128, wave 32x64, K=512 (8 iters).
__global__ __launch_bounds__(256) void pre_gemm(
    const __bf16* __restrict__ Xb, const __bf16* __restrict__ Bx,
    const float* __restrict__ bg, const float* __restrict__ bc,
    __bf16* __restrict__ Pg, __bf16* __restrict__ Pc) {
  __shared__ __bf16 Alds[64 * 72];
  __shared__ __bf16 Blds[8192];
  const int tid = threadIdx.x;
  const int lane = tid & 63;
  const int w = tid >> 6;
  const int wm = w >> 1, wn = w & 1;
  const int quad = lane >> 4, l16 = lane & 15;
  const int m0 = blockIdx.y * 64;
  const int n16b = blockIdx.x * 8;
  const int tz = blockIdx.z;

  const __bf16* gA[2];
  int ldsA[2];
#pragma unroll
  for (int i = 0; i < 2; ++i) {
    int c = tid + i * 256;
    gA[i] = Xb + (size_t)(m0 + (c >> 3)) * (T_SEQ * IND) + tz * IND + (c & 7) * 8;
    ldsA[i] = (c >> 3) * 72 + (c & 7) * 8;
  }
  const __bf16* gB[4];
  int ldsB[4];
#pragma unroll
  for (int i = 0; i < 4; ++i) {
    int c = tid + i * 256;
    int ks2c = c >> 9, rem = c & 511;
    gB[i] = Bx + (((size_t)(n16b + (rem >> 6)) * 16 + ks2c) * 64 + (rem & 63)) * 8;
    ldsB[i] = c * 8;
  }

  bf16x8 ra[2], rb[4];
#pragma unroll
  for (int i = 0; i < 2; ++i) ra[i] = *(const bf16x8*)(gA[i]);
#pragma unroll
  for (int i = 0; i < 4; ++i) rb[i] = *(const bf16x8*)(gB[i]);

  floatx4 acc[2][4] = {};
  for (int it = 0; it < 8; ++it) {
    __syncthreads();
#pragma unroll
    for (int i = 0; i < 2; ++i) *(bf16x8*)&Alds[ldsA[i]] = ra[i];
#pragma unroll
    for (int i = 0; i < 4; ++i) *(bf16x8*)&Blds[ldsB[i]] = rb[i];
    __syncthreads();
    if (it + 1 < 8) {
#pragma unroll
      for (int i = 0; i < 2; ++i) ra[i] = *(const bf16x8*)(gA[i] + (it + 1) * 64);
#pragma unroll
      for (int i = 0; i < 4; ++i) rb[i] = *(const bf16x8*)(gB[i] + (size_t)(it + 1) * 1024);
    }
#pragma unroll
    for (int ks2 = 0; ks2 < 2; ++ks2) {
      bf16x8 af[2], bfr[4];
#pragma unroll
      for (int mf = 0; mf < 2; ++mf)
        af[mf] = *(const bf16x8*)&Alds[(wm * 32 + mf * 16 + l16) * 72 + ks2 * 32 + quad * 8];
#pragma unroll
      for (int nf = 0; nf < 4; ++nf)
        bfr[nf] = *(const bf16x8*)&Blds[(ks2 * 512 + (wn * 4 + nf) * 64 + lane) * 8];
#pragma unroll
      for (int mf = 0; mf < 2; ++mf)
#pragma unroll
        for (int nf = 0; nf < 4; ++nf)
          acc[mf][nf] = __builtin_amdgcn_mfma_f32_16x16x32_bf16(af[mf], bfr[nf], acc[mf][nf], 0, 0, 0);
    }
  }

  const int m32 = (m0 >> 5) + wm;
  const int n64g = blockIdx.x * 2 + wn;
  const bool isg = (n64g < 32);
  __bf16* P = isg ? Pg : Pc;
  const float* bias = isg ? bg : bc;
  size_t tb = isg ? (((size_t)tz * 64 + m32) * 32 + n64g) * 2048
                  : (((size_t)tz * 64 + m32) * 16 + (n64g - 32)) * 2048;
  int colb = (isg ? n64g * 64 : (n64g - 32) * 64) + l16;
#pragma unroll
  for (int mf = 0; mf < 2; ++mf)
#pragma unroll
    for (int nf = 0; nf < 4; ++nf) {
      float bv = bias[colb + nf * 16];
      bf16x4 st;
#pragma unroll
      for (int i = 0; i < 4; ++i) st[i] = (__bf16)(acc[mf][nf][i] + bv);
      *(bf16x4*)&P[tb + (size_t)((mf * 4 + nf) * 64 + lane) * 4] = st;
    }
}

// ---------------- grid barrier (device-scope, capture-safe) ----------------
__device__ __forceinline__ void gsync(int* bar) {
  __syncthreads();
  if (threadIdx.x == 0) {
    __threadfence();
    int g = __hip_atomic_load(bar + 1, __ATOMIC_RELAXED, __HIP_MEMORY_SCOPE_AGENT);
    int a = __hip_atomic_fetch_add(bar, 1, __ATOMIC_ACQ_REL, __HIP_MEMORY_SCOPE_AGENT);
    if (a == NBLK - 1) {
      __hip_atomic_store(bar, 0, __ATOMIC_RELAXED, __HIP_MEMORY_SCOPE_AGENT);
      __hip_atomic_fetch_add(bar + 1, 1, __ATOMIC_RELEASE, __HIP_MEMORY_SCOPE_AGENT);
    } else {
      while (__hip_atomic_load(bar + 1, __ATOMIC_ACQUIRE, __HIP_MEMORY_SCOPE_AGENT) == g)
        __builtin_amdgcn_s_sleep(2);
    }
    __threadfence();
  }
  __syncthreads();
}

// ---------------- persistent recurrence kernel ----------------
// 512 blocks x 256 thr, 2 blocks/CU (co-resident). Per t:
//   gate phase: block tile 64x128 (nG=b&15, mG=b>>4), wave 32x64, K=1024
//   gsync
//   cand phase: block tile 64x64  (nC=b&15, mC=b>>4), wave 32x32, K=1024
//   gsync
// A-LDS XOR swizzle: elem(row,kchunk) at row*64 + ((kchunk^(row&7))*8).
__global__ __launch_bounds__(256, 2) void gru_persist(
    const __bf16* __restrict__ Bhg, const __bf16* __restrict__ Bhc,
    const __bf16* __restrict__ Pg, const __bf16* __restrict__ Pc,
    float* __restrict__ h32, __bf16* __restrict__ hb,
    float* __restrict__ u32, __bf16* __restrict__ rhb,
    float* __restrict__ out, int* __restrict__ bar) {
  __shared__ __bf16 Alds[64 * 64];
  __shared__ __bf16 Blds[128 * 64];
  const int tid = threadIdx.x;
  const int lane = tid & 63;
  const int w = tid >> 6;
  const int wm = w >> 1, wn = w & 1;
  const int quad = lane >> 4, l16 = lane & 15;
  const int b = blockIdx.x;
  const int nT = b & 15, mT = b >> 4;  // shared tile indices for both phases

  // ---- precomputed staging addresses (t-invariant) ----
  // gate A (hb): 64 rows x 64 k per iter, CA=2
  const __bf16* gAg[2];
  const __bf16* gAc[2];
  int ldsAo[2];
#pragma unroll
  for (int i = 0; i < 2; ++i) {
    int c = tid + i * 256;
    size_t off = (size_t)(mT * 64 + (c >> 3)) * HID + (c & 7) * 8;
    gAg[i] = hb + off;
    gAc[i] = rhb + off;
    ldsAo[i] = (c >> 3) * 64 + (((c & 7) ^ ((c >> 3) & 7)) * 8);
  }
  // gate B: 128 cols x 64 k per iter, CB=4; layout [ks2][n16(8)][lane]
  const __bf16* gBg[4];
  int ldsBg[4];
#pragma unroll
  for (int i = 0; i < 4; ++i) {
    int c = tid + i * 256;
    int ks2c = c >> 9, rem = c & 511;
    gBg[i] = Bhg + (((size_t)(nT * 8 + (rem >> 6)) * 32 + ks2c) * 64 + (rem & 63)) * 8;
    ldsBg[i] = c * 8;
  }
  // cand B: 64 cols x 64 k per iter, CB=2; layout [ks2][n16(4)][lane]
  const __bf16* gBc[2];
  int ldsBc[2];
#pragma unroll
  for (int i = 0; i < 2; ++i) {
    int c = tid + i * 256;
    int ks2c = c >> 8, rem = c & 255;
    gBc[i] = Bhc + (((size_t)(nT * 4 + (rem >> 6)) * 32 + ks2c) * 64 + (rem & 63)) * 8;
    ldsBc[i] = c * 8;
  }

  for (int t = 0; t < T_SEQ; ++t) {
    // ================= gate phase =================
    {
      bf16x8 ra[2], rb[4];
#pragma unroll
      for (int i = 0; i < 2; ++i) ra[i] = *(const bf16x8*)(gAg[i]);
#pragma unroll
      for (int i = 0; i < 4; ++i) rb[i] = *(const bf16x8*)(gBg[i]);
      floatx4 acc[2][4] = {};
      for (int it = 0; it < 16; ++it) {
        __syncthreads();
#pragma unroll
        for (int i = 0; i < 2; ++i) *(bf16x8*)&Alds[ldsAo[i]] = ra[i];
#pragma unroll
        for (int i = 0; i < 4; ++i) *(bf16x8*)&Blds[ldsBg[i]] = rb[i];
        __syncthreads();
        if (it + 1 < 16) {
#pragma unroll
          for (int i = 0; i < 2; ++i) ra[i] = *(const bf16x8*)(gAg[i] + (it + 1) * 64);
#pragma unroll
          for (int i = 0; i < 4; ++i) rb[i] = *(const bf16x8*)(gBg[i] + (size_t)(it + 1) * 1024);
        }
#pragma unroll
        for (int ks2 = 0; ks2 < 2; ++ks2) {
          bf16x8 af[2], bfr[4];
#pragma unroll
          for (int mf = 0; mf < 2; ++mf)
            af[mf] = *(const bf16x8*)&Alds[(wm * 32 + mf * 16 + l16) * 64 +
                                           (((ks2 * 4 + quad) ^ (l16 & 7)) * 8)];
#pragma unroll
          for (int nf = 0; nf < 4; ++nf)
            bfr[nf] = *(const bf16x8*)&Blds[(ks2 * 512 + (wn * 4 + nf) * 64 + lane) * 8];
#pragma unroll
          for (int mf = 0; mf < 2; ++mf)
#pragma unroll
            for (int nf = 0; nf < 4; ++nf)
              acc[mf][nf] = __builtin_amdgcn_mfma_f32_16x16x32_bf16(af[mf], bfr[nf], acc[mf][nf], 0, 0, 0);
        }
      }
      // epilogue
      const int m32 = mT * 2 + wm;
      const int n64 = nT * 2 + wn;
      const bool isr = (n64 < 16);
      size_t tb = (((size_t)t * 64 + m32) * 32 + n64) * 2048;
#pragma unroll
      for (int mf = 0; mf < 2; ++mf)
#pragma unroll
        for (int nf = 0; nf < 4; ++nf) {
          bf16x4 px = *(const bf16x4*)&Pg[tb + (size_t)((mf * 4 + nf) * 64 + lane) * 4];
          int col = nT * 128 + wn * 64 + nf * 16 + l16;
          int rowb = mT * 64 + wm * 32 + mf * 16 + quad * 4;
#pragma unroll
          for (int i = 0; i < 4; ++i) {
            float s = fast_sigmoid(acc[mf][nf][i] + (float)px[i]);
            if (isr) {
              size_t idx = (size_t)(rowb + i) * HID + col;
              rhb[idx] = (__bf16)(s * h32[idx]);
            } else {
              u32[(size_t)(rowb + i) * HID + (col - HID)] = s;
            }
          }
        }
    }
    gsync(bar);
    // ================= cand phase =================
    {
      bf16x8 ra[2], rb[2];
#pragma unroll
      for (int i = 0; i < 2; ++i) ra[i] = *(const bf16x8*)(gAc[i]);
#pragma unroll
      for (int i = 0; i < 2; ++i) rb[i] = *(const bf16x8*)(gBc[i]);
      floatx4 acc[2][2] = {};
      for (int it = 0; it < 16; ++it) {
        __syncthreads();
#pragma unroll
        for (int i = 0; i < 2; ++i) *(bf16x8*)&Alds[ldsAo[i]] = ra[i];
#pragma unroll
        for (int i = 0; i < 2; ++i) *(bf16x8*)&Blds[ldsBc[i]] = rb[i];
        __syncthreads();
        if (it + 1 < 16) {
#pragma unroll
          for (int i = 0; i < 2; ++i) ra[i] = *(const bf16x8*)(gAc[i] + (it + 1) * 64);
#pragma unroll
          for (int i = 0; i < 2; ++i) rb[i] = *(const bf16x8*)(gBc[i] + (size_t)(it + 1) * 1024);
        }
#pragma unroll
        for (int ks2 = 0; ks2 < 2; ++ks2) {
          bf16x8 af[2], bfr[2];
#pragma unroll
          for (int mf = 0; mf < 2; ++mf)
            af[mf] = *(const bf16x8*)&Alds[(wm * 32 + mf * 16 + l16) * 64 +
                                           (((ks2 * 4 + quad) ^ (l16 & 7)) * 8)];
#pragma unroll
          for (int nf = 0; nf < 2; ++nf)
            bfr[nf] = *(const bf16x8*)&Blds[(ks2 * 256 + (wn * 2 + nf) * 64 + lane) * 8];
#pragma unroll
          for (int mf = 0; mf < 2; ++mf)
#pragma unroll
            for (int nf = 0; nf < 2; ++nf)
              acc[mf][nf] = __builtin_amdgcn_mfma_f32_16x16x32_bf16(af[mf], bfr[nf], acc[mf][nf], 0, 0, 0);
        }
      }
      // epilogue: h update
      const int m32 = mT * 2 + wm;
      size_t tb = (((size_t)t * 64 + m32) * 16 + nT) * 2048;
#pragma unroll
      for (int mf = 0; mf < 2; ++mf)
#pragma unroll
        for (int nf = 0; nf < 2; ++nf) {
          bf16x4 px = *(const bf16x4*)&Pc[tb + (size_t)((mf * 4 + wn * 2 + nf) * 64 + lane) * 4];
          int col = nT * 64 + wn * 32 + nf * 16 + l16;
          int rowb = mT * 64 + wm * 32 + mf * 16 + quad * 4;
#pragma unroll
          for (int i = 0; i < 4; ++i) {
            float c = fast_tanh(acc[mf][nf][i] + (float)px[i]);
            size_t idx = (size_t)(rowb + i) * HID + col;
            float u = u32[idx];
            float hnew = u * h32[idx] + (1.f - u) * c;
            h32[idx] = hnew;
            hb[idx] = (__bf16)hnew;
            out[(size_t)(rowb + i) * (T_SEQ * HID) + t * HID + col] = hnew;
          }
        }
    }
    gsync(bar);
  }
}

extern "C" void kernel_launch(void* const* d_in, const int* in_sizes, int n_in,
                              void* d_out, int out_size, void* d_ws, size_t ws_size,
                              hipStream_t stream) {
  const float* x     = (const float*)d_in[0];
  const float* coded = (const float*)d_in[1];
  const float* Wg_f  = (const float*)d_in[2];
  const float* bg    = (const float*)d_in[3];
  const float* Wc_f  = (const float*)d_in[4];
  const float* bc    = (const float*)d_in[5];
  float* out = (float*)d_out;

  uintptr_t base = ((uintptr_t)d_ws + 255) & ~(uintptr_t)255;
  auto take = [&](size_t bytes) {
    void* p = (void*)base;
    base = (base + bytes + 255) & ~(uintptr_t)255;
    return p;
  };
  __bf16* Bx  = (__bf16*)take((size_t)(NPRE / 16) * 16 * 512 * 2);
  __bf16* Bhg = (__bf16*)take((size_t)(NGATE / 16) * 32 * 512 * 2);
  __bf16* Bhc = (__bf16*)take((size_t)(HID / 16) * 32 * 512 * 2);
  __bf16* Xb  = (__bf16*)take((size_t)BATCH * T_SEQ * IND * 2);
  __bf16* Pg  = (__bf16*)take((size_t)T_SEQ * 64 * 32 * 2048 * 2);
  __bf16* Pc  = (__bf16*)take((size_t)T_SEQ * 64 * 16 * 2048 * 2);
  float*  h32 = (float*) take((size_t)BATCH * HID * 4);
  __bf16* hb  = (__bf16*)take((size_t)BATCH * HID * 2);
  float*  u32 = (float*) take((size_t)BATCH * HID * 4);
  __bf16* rhb = (__bf16*)take((size_t)BATCH * HID * 2);
  int*    bar = (int*)   take(256);

  hipMemsetAsync(bar, 0, 256, stream);
  pack_w<<<(NGATE / 16) * 16 * 64 / 256, 256, 0, stream>>>(Wg_f, NGATE, 0, 16, Bx);
  pack_w<<<(HID / 16) * 16 * 64 / 256, 256, 0, stream>>>(
      Wc_f, HID, 0, 16, Bx + (size_t)(NGATE / 16) * 16 * 512);
  pack_w<<<(NGATE / 16) * 32 * 64 / 256, 256, 0, stream>>>(Wg_f, NGATE, IND, 32, Bhg);
  pack_w<<<(HID / 16) * 32 * 64 / 256, 256, 0, stream>>>(Wc_f, HID, IND, 32, Bhc);
  cvt_bf16<<<(BATCH * T_SEQ * IND / 4 + 255) / 256, 256, 0, stream>>>(
      (const float4*)x, Xb, BATCH * T_SEQ * IND / 4);
  init_h<<<(BATCH * HID / 4 + 255) / 256, 256, 0, stream>>>(
      (const float4*)coded, (float4*)h32, hb, BATCH * HID / 4);

  pre_gemm<<<dim3(NPRE / 128, BATCH / 64, T_SEQ), 256, 0, stream>>>(Xb, Bx, bg, bc, Pg, Pc);

  gru_persist<<<NBLK, 256, 0, stream>>>(Bhg, Bhc, Pg, Pc, h32, hb, u32, rhb, out, bar);
}

// Round 5
// 975.982 us; speedup vs baseline: 3.8444x; 3.8444x over previous
//
#include <hip/hip_runtime.h>
#include <hip/hip_bf16.h>

// GRU (TF GRUCell), B=2048, T=12, D=512, H=1024, fp32 in/out.
// R5: revert to R3 multi-launch (persistent grid-sync = L2 flush on this
// chip -> catastrophic). Improvements: pre_gemm 128x128 m97-style with fused
// fp32->bf16 x conversion; step kernels get depth-3 register prefetch;
// packs fused into one dispatch. XOR-swizzled A-LDS (measured conflict-free).

#define T_SEQ 12
#define BATCH 2048
#define IND 512
#define HID 1024
#define NGATE (2 * HID)  // 2048
#define NPRE (NGATE + HID)

typedef __bf16 bf16x8 __attribute__((ext_vector_type(8)));
typedef __bf16 bf16x4 __attribute__((ext_vector_type(4)));
typedef float floatx4 __attribute__((ext_vector_type(4)));

__device__ __forceinline__ float fast_sigmoid(float v) {
  v = fminf(30.f, fmaxf(-30.f, v));
  return 1.f / (1.f + __expf(-v));
}
__device__ __forceinline__ float fast_tanh(float v) {
  v = fminf(15.f, fmaxf(-15.f, v));
  float e = __expf(2.f * v);
  return (e - 1.f) / (e + 1.f);
}

// ---- pack all 4 weight regions in one dispatch ----
// B-frag order: out[wid*512 + lane*8 + j] = W[row0 + kt*32 + (lane>>4)*8 + j][n16*16 + (lane&15)]
__global__ __launch_bounds__(256) void pack_all(
    const float* __restrict__ Wg, const float* __restrict__ Wc,
    __bf16* __restrict__ Bx, __bf16* __restrict__ Bhg, __bf16* __restrict__ Bhc) {
  int gid = blockIdx.x * 256 + threadIdx.x;
  int g = gid >> 6, lane = gid & 63;
  const float* W; int ld, row0, ksteps, wid; __bf16* out;
  if (g < 2048)      { W = Wg; ld = NGATE; row0 = 0;   ksteps = 16; wid = g;        out = Bx; }
  else if (g < 3072) { W = Wc; ld = HID;   row0 = 0;   ksteps = 16; wid = g - 2048; out = Bx + (size_t)2048 * 512; }
  else if (g < 7168) { W = Wg; ld = NGATE; row0 = IND; ksteps = 32; wid = g - 3072; out = Bhg; }
  else               { W = Wc; ld = HID;   row0 = IND; ksteps = 32; wid = g - 7168; out = Bhc; }
  int n16 = wid / ksteps, kt = wid - n16 * ksteps;
  int col = n16 * 16 + (lane & 15);
  int k0 = row0 + kt * 32 + (lane >> 4) * 8;
  bf16x8 v;
#pragma unroll
  for (int j = 0; j < 8; ++j) v[j] = (__bf16)W[(size_t)(k0 + j) * ld + col];
  *reinterpret_cast<bf16x8*>(out + (size_t)wid * 512 + lane * 8) = v;
}

__global__ void init_h(const float4* __restrict__ coded, float4* __restrict__ h32,
                       __bf16* __restrict__ hb, int n4) {
  int i = blockIdx.x * blockDim.x + threadIdx.x;
  if (i >= n4) return;
  float4 v = coded[i];
  h32[i] = v;
  bf16x4 o;
  o[0] = (__bf16)v.x; o[1] = (__bf16)v.y; o[2] = (__bf16)v.z; o[3] = (__bf16)v.w;
  *reinterpret_cast<bf16x4*>(hb + (size_t)i * 4) = o;
}

// ---- Px precompute: 128x128 block tile, wave 64x64 (4x4 frags), K=512 ----
// Reads x fp32 directly (fused conversion). grid(24, 16, 12), 256 thr.
// A-LDS XOR swizzle: elem(row, chunk) at row*64 + ((chunk^(row&7))*8).
__global__ __launch_bounds__(256) void pre_gemm(
    const float* __restrict__ x, const __bf16* __restrict__ Bx,
    const float* __restrict__ bg, const float* __restrict__ bc,
    __bf16* __restrict__ Pg, __bf16* __restrict__ Pc) {
  __shared__ __bf16 Alds[128 * 64];  // 16 KB
  __shared__ __bf16 Blds[8192];      // 16 KB
  const int tid = threadIdx.x, lane = tid & 63, w = tid >> 6;
  const int wm = w >> 1, wn = w & 1, quad = lane >> 4, l16 = lane & 15;
  const int m0 = blockIdx.y * 128;
  const int n16b = blockIdx.x * 8;
  const int tz = blockIdx.z;

  const float* gA[4];
  int ldsA[4];
#pragma unroll
  for (int i = 0; i < 4; ++i) {
    int c = tid + i * 256;  // [0,1024): row=c>>3 (0..127), k8=c&7
    gA[i] = x + ((size_t)(m0 + (c >> 3)) * T_SEQ + tz) * IND + (c & 7) * 8;
    ldsA[i] = (c >> 3) * 64 + (((c & 7) ^ ((c >> 3) & 7)) * 8);
  }
  const __bf16* gB[4];
  int ldsB[4];
#pragma unroll
  for (int i = 0; i < 4; ++i) {
    int c = tid + i * 256;
    int ks2c = c >> 9, rem = c & 511;
    gB[i] = Bx + (((size_t)(n16b + (rem >> 6)) * 16 + ks2c) * 64 + (rem & 63)) * 8;
    ldsB[i] = c * 8;
  }

  floatx4 ra0[4], ra1[4];
  bf16x8 rb[4];
#pragma unroll
  for (int i = 0; i < 4; ++i) {
    ra0[i] = *(const floatx4*)(gA[i]);
    ra1[i] = *(const floatx4*)(gA[i] + 4);
  }
#pragma unroll
  for (int i = 0; i < 4; ++i) rb[i] = *(const bf16x8*)(gB[i]);

  floatx4 acc[4][4] = {};
  for (int it = 0; it < 8; ++it) {
    __syncthreads();
#pragma unroll
    for (int i = 0; i < 4; ++i) {
      bf16x8 cv;
#pragma unroll
      for (int j = 0; j < 4; ++j) { cv[j] = (__bf16)ra0[i][j]; cv[j + 4] = (__bf16)ra1[i][j]; }
      *(bf16x8*)&Alds[ldsA[i]] = cv;
    }
#pragma unroll
    for (int i = 0; i < 4; ++i) *(bf16x8*)&Blds[ldsB[i]] = rb[i];
    __syncthreads();
    if (it + 1 < 8) {
#pragma unroll
      for (int i = 0; i < 4; ++i) {
        ra0[i] = *(const floatx4*)(gA[i] + (it + 1) * 64);
        ra1[i] = *(const floatx4*)(gA[i] + (it + 1) * 64 + 4);
      }
#pragma unroll
      for (int i = 0; i < 4; ++i) rb[i] = *(const bf16x8*)(gB[i] + (size_t)(it + 1) * 1024);
    }
#pragma unroll
    for (int ks2 = 0; ks2 < 2; ++ks2) {
      bf16x8 af[4], bfr[4];
#pragma unroll
      for (int mf = 0; mf < 4; ++mf) {
        int row = wm * 64 + mf * 16 + l16;
        af[mf] = *(const bf16x8*)&Alds[row * 64 + (((ks2 * 4 + quad) ^ (row & 7)) * 8)];
      }
#pragma unroll
      for (int nf = 0; nf < 4; ++nf)
        bfr[nf] = *(const bf16x8*)&Blds[(ks2 * 512 + (wn * 4 + nf) * 64 + lane) * 8];
#pragma unroll
      for (int mf = 0; mf < 4; ++mf)
#pragma unroll
        for (int nf = 0; nf < 4; ++nf)
          acc[mf][nf] = __builtin_amdgcn_mfma_f32_16x16x32_bf16(af[mf], bfr[nf], acc[mf][nf], 0, 0, 0);
    }
  }

  const int n64g = blockIdx.x * 2 + wn;
  const bool isg = (n64g < 32);
  __bf16* P = isg ? Pg : Pc;
  const float* bias = isg ? bg : bc;
  const int nrel = isg ? n64g : (n64g - 32);
  const int colb = nrel * 64 + l16;
#pragma unroll
  for (int mf = 0; mf < 4; ++mf) {
    int m32 = blockIdx.y * 4 + wm * 2 + (mf >> 1);
    size_t tb = isg ? (((size_t)tz * 64 + m32) * 32 + n64g) * 2048
                    : (((size_t)tz * 64 + m32) * 16 + nrel) * 2048;
#pragma unroll
    for (int nf = 0; nf < 4; ++nf) {
      float bv = bias[colb + nf * 16];
      bf16x4 st;
#pragma unroll
      for (int i = 0; i < 4; ++i) st[i] = (__bf16)(acc[mf][nf][i] + bv);
      *(bf16x4*)&P[tb + (size_t)(((mf & 1) * 4 + nf) * 64 + lane) * 4] = st;
    }
  }
}

// ---- gate step: 64x128 tile, 4 waves, K=1024, depth-3 reg prefetch ----
__global__ __launch_bounds__(256, 2) void gate_step(
    const __bf16* __restrict__ hb, const __bf16* __restrict__ Bhg,
    const __bf16* __restrict__ Pg, const float* __restrict__ h32,
    float* __restrict__ u32, __bf16* __restrict__ rhb, int t) {
  __shared__ __bf16 Alds[64 * 64];  // 8 KB
  __shared__ __bf16 Blds[8192];     // 16 KB
  const int tid = threadIdx.x, lane = tid & 63, w = tid >> 6;
  const int wm = w >> 1, wn = w & 1, quad = lane >> 4, l16 = lane & 15;
  const int nT = blockIdx.x, mT = blockIdx.y;

  const __bf16* gA[2];
  int ldsA[2];
#pragma unroll
  for (int i = 0; i < 2; ++i) {
    int c = tid + i * 256;  // [0,512): row=c>>3 (0..63), k8=c&7
    gA[i] = hb + (size_t)(mT * 64 + (c >> 3)) * HID + (c & 7) * 8;
    ldsA[i] = (c >> 3) * 64 + (((c & 7) ^ ((c >> 3) & 7)) * 8);
  }
  const __bf16* gB[4];
  int ldsB[4];
#pragma unroll
  for (int i = 0; i < 4; ++i) {
    int c = tid + i * 256;
    int ks2c = c >> 9, rem = c & 511;
    gB[i] = Bhg + (((size_t)(nT * 8 + (rem >> 6)) * 32 + ks2c) * 64 + (rem & 63)) * 8;
    ldsB[i] = c * 8;
  }

  bf16x8 ra[3][2], rb[3][4];
#pragma unroll
  for (int s = 0; s < 3; ++s) {
#pragma unroll
    for (int i = 0; i < 2; ++i) ra[s][i] = *(const bf16x8*)(gA[i] + s * 64);
#pragma unroll
    for (int i = 0; i < 4; ++i) rb[s][i] = *(const bf16x8*)(gB[i] + (size_t)s * 1024);
  }

  floatx4 acc[2][4] = {};
#pragma unroll
  for (int it = 0; it < 16; ++it) {
    const int st = it % 3;
    __syncthreads();
#pragma unroll
    for (int i = 0; i < 2; ++i) *(bf16x8*)&Alds[ldsA[i]] = ra[st][i];
#pragma unroll
    for (int i = 0; i < 4; ++i) *(bf16x8*)&Blds[ldsB[i]] = rb[st][i];
    __syncthreads();
    if (it + 3 < 16) {
#pragma unroll
      for (int i = 0; i < 2; ++i) ra[st][i] = *(const bf16x8*)(gA[i] + (it + 3) * 64);
#pragma unroll
      for (int i = 0; i < 4; ++i) rb[st][i] = *(const bf16x8*)(gB[i] + (size_t)(it + 3) * 1024);
    }
#pragma unroll
    for (int ks2 = 0; ks2 < 2; ++ks2) {
      bf16x8 af[2], bfr[4];
#pragma unroll
      for (int mf = 0; mf < 2; ++mf) {
        int row = wm * 32 + mf * 16 + l16;
        af[mf] = *(const bf16x8*)&Alds[row * 64 + (((ks2 * 4 + quad) ^ (row & 7)) * 8)];
      }
#pragma unroll
      for (int nf = 0; nf < 4; ++nf)
        bfr[nf] = *(const bf16x8*)&Blds[(ks2 * 512 + (wn * 4 + nf) * 64 + lane) * 8];
#pragma unroll
      for (int mf = 0; mf < 2; ++mf)
#pragma unroll
        for (int nf = 0; nf < 4; ++nf)
          acc[mf][nf] = __builtin_amdgcn_mfma_f32_16x16x32_bf16(af[mf], bfr[nf], acc[mf][nf], 0, 0, 0);
    }
  }

  const int m32 = mT * 2 + wm;
  const int n64 = nT * 2 + wn;
  const bool isr = (n64 < 16);
  size_t tb = (((size_t)t * 64 + m32) * 32 + n64) * 2048;
#pragma unroll
  for (int mf = 0; mf < 2; ++mf)
#pragma unroll
    for (int nf = 0; nf < 4; ++nf) {
      bf16x4 px = *(const bf16x4*)&Pg[tb + (size_t)((mf * 4 + nf) * 64 + lane) * 4];
      int col = nT * 128 + wn * 64 + nf * 16 + l16;
      int rowb = mT * 64 + wm * 32 + mf * 16 + quad * 4;
#pragma unroll
      for (int i = 0; i < 4; ++i) {
        float s = fast_sigmoid(acc[mf][nf][i] + (float)px[i]);
        if (isr) {
          size_t idx = (size_t)(rowb + i) * HID + col;
          rhb[idx] = (__bf16)(s * h32[idx]);
        } else {
          u32[(size_t)(rowb + i) * HID + (col - HID)] = s;
        }
      }
    }
}

// ---- cand step: 64x64 tile, 2 waves, K=1024, depth-3 reg prefetch ----
__global__ __launch_bounds__(128, 2) void cand_step(
    const __bf16* __restrict__ rhb, const __bf16* __restrict__ Bhc,
    const __bf16* __restrict__ Pc, const float* __restrict__ u32,
    float* __restrict__ h32, __bf16* __restrict__ hb,
    float* __restrict__ out, int t) {
  __shared__ __bf16 Alds[64 * 64];  // 8 KB
  __shared__ __bf16 Blds[4096];     // 8 KB
  const int tid = threadIdx.x, lane = tid & 63, wm = tid >> 6;
  const int quad = lane >> 4, l16 = lane & 15;
  const int nT = blockIdx.x, mT = blockIdx.y;

  const __bf16* gA[4];
  int ldsA[4];
#pragma unroll
  for (int i = 0; i < 4; ++i) {
    int c = tid + i * 128;  // [0,512)
    gA[i] = rhb + (size_t)(mT * 64 + (c >> 3)) * HID + (c & 7) * 8;
    ldsA[i] = (c >> 3) * 64 + (((c & 7) ^ ((c >> 3) & 7)) * 8);
  }
  const __bf16* gB[4];
  int ldsB[4];
#pragma unroll
  for (int i = 0; i < 4; ++i) {
    int c = tid + i * 128;  // [0,512)
    int ks2c = c >> 8, rem = c & 255;
    gB[i] = Bhc + (((size_t)(nT * 4 + (rem >> 6)) * 32 + ks2c) * 64 + (rem & 63)) * 8;
    ldsB[i] = c * 8;
  }

  bf16x8 ra[3][4], rb[3][4];
#pragma unroll
  for (int s = 0; s < 3; ++s) {
#pragma unroll
    for (int i = 0; i < 4; ++i) {
      ra[s][i] = *(const bf16x8*)(gA[i] + s * 64);
      rb[s][i] = *(const bf16x8*)(gB[i] + (size_t)s * 1024);
    }
  }

  floatx4 acc[2][4] = {};
#pragma unroll
  for (int it = 0; it < 16; ++it) {
    const int st = it % 3;
    __syncthreads();
#pragma unroll
    for (int i = 0; i < 4; ++i) {
      *(bf16x8*)&Alds[ldsA[i]] = ra[st][i];
      *(bf16x8*)&Blds[ldsB[i]] = rb[st][i];
    }
    __syncthreads();
    if (it + 3 < 16) {
#pragma unroll
      for (int i = 0; i < 4; ++i) {
        ra[st][i] = *(const bf16x8*)(gA[i] + (it + 3) * 64);
        rb[st][i] = *(const bf16x8*)(gB[i] + (size_t)(it + 3) * 1024);
      }
    }
#pragma unroll
    for (int ks2 = 0; ks2 < 2; ++ks2) {
      bf16x8 af[2], bfr[4];
#pragma unroll
      for (int mf = 0; mf < 2; ++mf) {
        int row = wm * 32 + mf * 16 + l16;
        af[mf] = *(const bf16x8*)&Alds[row * 64 + (((ks2 * 4 + quad) ^ (row & 7)) * 8)];
      }
#pragma unroll
      for (int nf = 0; nf < 4; ++nf)
        bfr[nf] = *(const bf16x8*)&Blds[(ks2 * 256 + nf * 64 + lane) * 8];
#pragma unroll
      for (int mf = 0; mf < 2; ++mf)
#pragma unroll
        for (int nf = 0; nf < 4; ++nf)
          acc[mf][nf] = __builtin_amdgcn_mfma_f32_16x16x32_bf16(af[mf], bfr[nf], acc[mf][nf], 0, 0, 0);
    }
  }

  const int m32 = mT * 2 + wm;
  size_t tb = (((size_t)t * 64 + m32) * 16 + nT) * 2048;
#pragma unroll
  for (int mf = 0; mf < 2; ++mf)
#pragma unroll
    for (int nf = 0; nf < 4; ++nf) {
      bf16x4 px = *(const bf16x4*)&Pc[tb + (size_t)((mf * 4 + nf) * 64 + lane) * 4];
      int col = nT * 64 + nf * 16 + l16;
      int rowb = mT * 64 + wm * 32 + mf * 16 + quad * 4;
#pragma unroll
      for (int i = 0; i < 4; ++i) {
        float c = fast_tanh(acc[mf][nf][i] + (float)px[i]);
        size_t idx = (size_t)(rowb + i) * HID + col;
        float u = u32[idx];
        float hnew = u * h32[idx] + (1.f - u) * c;
        h32[idx] = hnew;
        hb[idx] = (__bf16)hnew;
        out[(size_t)(rowb + i) * (T_SEQ * HID) + t * HID + col] = hnew;
      }
    }
}

extern "C" void kernel_launch(void* const* d_in, const int* in_sizes, int n_in,
                              void* d_out, int out_size, void* d_ws, size_t ws_size,
                              hipStream_t stream) {
  const float* x     = (const float*)d_in[0];
  const float* coded = (const float*)d_in[1];
  const float* Wg_f  = (const float*)d_in[2];
  const float* bg    = (const float*)d_in[3];
  const float* Wc_f  = (const float*)d_in[4];
  const float* bc    = (const float*)d_in[5];
  float* out = (float*)d_out;

  uintptr_t base = ((uintptr_t)d_ws + 255) & ~(uintptr_t)255;
  auto take = [&](size_t bytes) {
    void* p = (void*)base;
    base = (base + bytes + 255) & ~(uintptr_t)255;
    return p;
  };
  __bf16* Bx  = (__bf16*)take((size_t)(NPRE / 16) * 16 * 512 * 2);   // 3.1 MB
  __bf16* Bhg = (__bf16*)take((size_t)(NGATE / 16) * 32 * 512 * 2);  // 4.2 MB
  __bf16* Bhc = (__bf16*)take((size_t)(HID / 16) * 32 * 512 * 2);    // 2.1 MB
  __bf16* Pg  = (__bf16*)take((size_t)T_SEQ * 64 * 32 * 2048 * 2);   // 100.7 MB
  __bf16* Pc  = (__bf16*)take((size_t)T_SEQ * 64 * 16 * 2048 * 2);   // 50.3 MB
  float*  h32 = (float*) take((size_t)BATCH * HID * 4);
  __bf16* hb  = (__bf16*)take((size_t)BATCH * HID * 2);
  float*  u32 = (float*) take((size_t)BATCH * HID * 4);
  __bf16* rhb = (__bf16*)take((size_t)BATCH * HID * 2);

  pack_all<<<2304, 256, 0, stream>>>(Wg_f, Wc_f, Bx, Bhg, Bhc);
  init_h<<<BATCH * HID / 4 / 256, 256, 0, stream>>>(
      (const float4*)coded, (float4*)h32, hb, BATCH * HID / 4);

  pre_gemm<<<dim3(NPRE / 128, BATCH / 128, T_SEQ), 256, 0, stream>>>(
      x, Bx, bg, bc, Pg, Pc);

  for (int t = 0; t < T_SEQ; ++t) {
    gate_step<<<dim3(16, 32), 256, 0, stream>>>(hb, Bhg, Pg, h32, u32, rhb, t);
    cand_step<<<dim3(16, 32), 128, 0, stream>>>(rhb, Bhc, Pc, u32, h32, hb, out, t);
  }
}